// Round 1
// baseline (903.245 us; speedup 1.0000x reference)
//
#include <hip/hip_runtime.h>

#define BATCH 16
#define CH    256
#define NPT   2048
#define DQK   32
#define OTOT  320   // 32 q + 32 k + 256 v
#define EPSB  1e-5f
#define SLOPE 0.2f

#define TN 64
#define TM 32

// ---------------------------------------------------------------------------
// Kernel 1: raw conv1x1 for q/k/v combined: Y[b, o, n], o in [0,320)
// grid (N/256, 80, B), block 256. Each block: 4 consecutive o's, 256 n's.
__global__ __launch_bounds__(256) void conv_kernel(
    const float* __restrict__ x,
    const float* __restrict__ qw, const float* __restrict__ qb,
    const float* __restrict__ kw, const float* __restrict__ kb,
    const float* __restrict__ vw, const float* __restrict__ vb,
    float* __restrict__ Y)
{
    int n  = blockIdx.x * 256 + threadIdx.x;
    int o0 = blockIdx.y * 4;
    int b  = blockIdx.z;

    const float* wbase; const float* bbase; int oo;
    if (o0 < 32)      { wbase = qw; bbase = qb; oo = o0;      }
    else if (o0 < 64) { wbase = kw; bbase = kb; oo = o0 - 32; }
    else              { wbase = vw; bbase = vb; oo = o0 - 64; }
    const float* w0 = wbase + oo * CH;

    const float* xb = x + ((size_t)b * CH) * NPT + n;
    float a0 = 0.f, a1 = 0.f, a2 = 0.f, a3 = 0.f;
#pragma unroll 8
    for (int c = 0; c < CH; ++c) {
        float xv = xb[(size_t)c * NPT];
        a0 += w0[c]          * xv;
        a1 += w0[CH + c]     * xv;
        a2 += w0[2*CH + c]   * xv;
        a3 += w0[3*CH + c]   * xv;
    }
    float* yb = Y + ((size_t)b * OTOT + o0) * NPT + n;
    yb[0]        = a0 + bbase[oo];
    yb[NPT]      = a1 + bbase[oo + 1];
    yb[2*NPT]    = a2 + bbase[oo + 2];
    yb[3*NPT]    = a3 + bbase[oo + 3];
}

// ---------------------------------------------------------------------------
// Kernel 2: per-channel BN stats over (B, N) -> scale A[o], shift Cc[o]
// grid 320, block 256.
__global__ __launch_bounds__(256) void stats_kernel(
    const float* __restrict__ Y,
    const float* __restrict__ qg, const float* __restrict__ qbe,
    const float* __restrict__ kg, const float* __restrict__ kbe,
    const float* __restrict__ vg, const float* __restrict__ vbe,
    float* __restrict__ A, float* __restrict__ Cc)
{
    int o = blockIdx.x;
    float s = 0.f, ss = 0.f;
    for (int t = threadIdx.x; t < BATCH * NPT; t += 256) {
        int b = t >> 11, n = t & (NPT - 1);
        float v = Y[((size_t)b * OTOT + o) * NPT + n];
        s += v; ss += v * v;
    }
#pragma unroll
    for (int off = 32; off; off >>= 1) {
        s  += __shfl_down(s, off);
        ss += __shfl_down(ss, off);
    }
    __shared__ float ls[4], lss[4];
    int w = threadIdx.x >> 6, lane = threadIdx.x & 63;
    if (lane == 0) { ls[w] = s; lss[w] = ss; }
    __syncthreads();
    if (threadIdx.x == 0) {
        float S  = ls[0] + ls[1] + ls[2] + ls[3];
        float SS = lss[0] + lss[1] + lss[2] + lss[3];
        const float inv = 1.0f / (BATCH * NPT);
        float mean = S * inv;
        float var  = SS * inv - mean * mean;   // biased, matches reference
        float g, be;
        if (o < 32)      { g = qg[o];      be = qbe[o];      }
        else if (o < 64) { g = kg[o - 32]; be = kbe[o - 32]; }
        else             { g = vg[o - 64]; be = vbe[o - 64]; }
        float a = g * rsqrtf(var + EPSB);
        A[o]  = a;
        Cc[o] = be - mean * a;
    }
}

// ---------------------------------------------------------------------------
// Kernel 3: in-place normalize (+LeakyReLU on v channels).
// grid 40960, block 256 — each block covers 256 contiguous elems, o uniform.
__global__ __launch_bounds__(256) void norm_kernel(
    float* __restrict__ Y, const float* __restrict__ A, const float* __restrict__ Cc)
{
    size_t idx = (size_t)blockIdx.x * 256 + threadIdx.x;
    int o = (int)((idx >> 11) % OTOT);
    float v = Y[idx] * A[o] + Cc[o];
    if (o >= 64) v = (v > 0.f) ? v : SLOPE * v;
    Y[idx] = v;
}

// ---------------------------------------------------------------------------
// Kernel 4: flash-style attention + residual.
// grid (N/TN, B), block 256.
// Thread register tile: 8 c x 8 i (c = cc*32 + tc, i = ti*8 + ii).
__global__ __launch_bounds__(256) void attn_kernel(
    const float* __restrict__ Y, const float* __restrict__ x, float* __restrict__ out)
{
    int b  = blockIdx.y;
    int n0 = blockIdx.x * TN;
    const float* Q = Y + ((size_t)b * OTOT + 0)  * NPT;
    const float* K = Y + ((size_t)b * OTOT + 32) * NPT;
    const float* V = Y + ((size_t)b * OTOT + 64) * NPT;

    __shared__ float qs[DQK * TN];       // [d][i]
    __shared__ float ks[DQK * TM];       // [d][j]
    __shared__ float Ps[TM * TN];        // [j][i] raw scores then p
    __shared__ float vs[TM * 257];       // [j][c], stride 257 -> conflict-free
    __shared__ float Mrow[TN], Srow[TN], Alph[TN];

    int tid = threadIdx.x;
    int tc = tid & 31, ti = tid >> 5;    // accum mapping
    int sj = tid & 7,  si = tid >> 3;    // score mapping

    for (int e = tid; e < DQK * TN; e += 256) {
        int d = e >> 6, i = e & 63;
        qs[e] = Q[(size_t)d * NPT + n0 + i];
    }
    if (tid < TN) { Mrow[tid] = -__builtin_inff(); Srow[tid] = 0.f; }

    float O[8][8];
#pragma unroll
    for (int a = 0; a < 8; ++a)
#pragma unroll
        for (int bb = 0; bb < 8; ++bb) O[a][bb] = 0.f;

    __syncthreads();

    for (int mt = 0; mt < NPT / TM; ++mt) {
        int m0 = mt * TM;
        // stage K-tile and V-tile
        for (int e = tid; e < DQK * TM; e += 256) {
            int d = e >> 5, j = e & 31;
            ks[d * TM + j] = K[(size_t)d * NPT + m0 + j];
        }
        for (int e = tid; e < CH * TM; e += 256) {
            int c = e >> 5, j = e & 31;
            vs[j * 257 + c] = V[(size_t)c * NPT + m0 + j];
        }
        __syncthreads();

        // scores: thread computes 2i x 4j
        float sc[2][4] = {{0.f,0.f,0.f,0.f},{0.f,0.f,0.f,0.f}};
#pragma unroll
        for (int d = 0; d < DQK; ++d) {
            float2 q2 = *(const float2*)&qs[d * TN + si * 2];
            float4 k4 = *(const float4*)&ks[d * TM + sj * 4];
            sc[0][0] += q2.x * k4.x; sc[0][1] += q2.x * k4.y;
            sc[0][2] += q2.x * k4.z; sc[0][3] += q2.x * k4.w;
            sc[1][0] += q2.y * k4.x; sc[1][1] += q2.y * k4.y;
            sc[1][2] += q2.y * k4.z; sc[1][3] += q2.y * k4.w;
        }
#pragma unroll
        for (int jj = 0; jj < 4; ++jj)
#pragma unroll
            for (int ii = 0; ii < 2; ++ii)
                Ps[(sj * 4 + jj) * TN + si * 2 + ii] = sc[ii][jj];
        __syncthreads();

        // online softmax, one row per thread (wave 0)
        if (tid < TN) {
            int i = tid;
            float mo = Mrow[i];
            float tmax = -__builtin_inff();
            for (int j = 0; j < TM; ++j) tmax = fmaxf(tmax, Ps[j * TN + i]);
            float mn = fmaxf(mo, tmax);
            float al = __expf(mo - mn);
            float tsum = 0.f;
            for (int j = 0; j < TM; ++j) {
                float p = __expf(Ps[j * TN + i] - mn);
                Ps[j * TN + i] = p;
                tsum += p;
            }
            Mrow[i] = mn;
            Srow[i] = Srow[i] * al + tsum;
            Alph[i] = al;
        }
        __syncthreads();

        // rescale + accumulate O += V * P^T
        float al[8];
#pragma unroll
        for (int ii = 0; ii < 8; ++ii) al[ii] = Alph[ti * 8 + ii];
#pragma unroll
        for (int cc = 0; cc < 8; ++cc)
#pragma unroll
            for (int ii = 0; ii < 8; ++ii) O[cc][ii] *= al[ii];

        for (int j = 0; j < TM; ++j) {
            float4 pa = *(const float4*)&Ps[j * TN + ti * 8];
            float4 pb = *(const float4*)&Ps[j * TN + ti * 8 + 4];
            float p[8] = {pa.x, pa.y, pa.z, pa.w, pb.x, pb.y, pb.z, pb.w};
#pragma unroll
            for (int cc = 0; cc < 8; ++cc) {
                float v = vs[j * 257 + cc * 32 + tc];
#pragma unroll
                for (int ii = 0; ii < 8; ++ii) O[cc][ii] += v * p[ii];
            }
        }
        __syncthreads();
    }

    // epilogue: divide by softmax denom, stage via LDS, coalesced store + residual
    float rs[8];
#pragma unroll
    for (int ii = 0; ii < 8; ++ii) rs[ii] = 1.0f / Srow[ti * 8 + ii];

    for (int cc = 0; cc < 8; ++cc) {
        __syncthreads();
#pragma unroll
        for (int ii = 0; ii < 8; ++ii)
            vs[tc * 257 + ti * 8 + ii] = O[cc][ii] * rs[ii];
        __syncthreads();
        for (int e = tid; e < 32 * TN; e += 256) {
            int r = e >> 6, col = e & 63;
            int c = cc * 32 + r;
            size_t gi = ((size_t)b * CH + c) * NPT + n0 + col;
            out[gi] = vs[r * 257 + col] + x[gi];
        }
    }
}

// ---------------------------------------------------------------------------
extern "C" void kernel_launch(void* const* d_in, const int* in_sizes, int n_in,
                              void* d_out, int out_size, void* d_ws, size_t ws_size,
                              hipStream_t stream)
{
    const float* x   = (const float*)d_in[0];
    const float* qw  = (const float*)d_in[1];
    const float* qb  = (const float*)d_in[2];
    const float* qg  = (const float*)d_in[3];
    const float* qbe = (const float*)d_in[4];
    const float* kw  = (const float*)d_in[5];
    const float* kb  = (const float*)d_in[6];
    const float* kg  = (const float*)d_in[7];
    const float* kbe = (const float*)d_in[8];
    const float* vw  = (const float*)d_in[9];
    const float* vb  = (const float*)d_in[10];
    const float* vg  = (const float*)d_in[11];
    const float* vbe = (const float*)d_in[12];
    float* out = (float*)d_out;

    // ws layout: Y [16*320*2048] fp32 (41.9 MB) | A[320] | Cc[320]
    float* Y  = (float*)d_ws;
    float* A  = Y + (size_t)BATCH * OTOT * NPT;
    float* Cc = A + OTOT;

    conv_kernel <<<dim3(NPT / 256, OTOT / 4, BATCH), 256, 0, stream>>>(x, qw, qb, kw, kb, vw, vb, Y);
    stats_kernel<<<OTOT, 256, 0, stream>>>(Y, qg, qbe, kg, kbe, vg, vbe, A, Cc);
    norm_kernel <<<(BATCH * OTOT * NPT) / 256, 256, 0, stream>>>(Y, A, Cc);
    attn_kernel <<<dim3(NPT / TN, BATCH), 256, 0, stream>>>(Y, x, out);
}

// Round 2
// 301.466 us; speedup vs baseline: 2.9962x; 2.9962x over previous
//
#include <hip/hip_runtime.h>

#define BATCH 16
#define CH    256
#define NPT   2048
#define DQK   32
#define OTOT  320   // 32 q + 32 k + 256 v
#define EPSB  1e-5f
#define SLOPE 0.2f

typedef __attribute__((ext_vector_type(8))) short bf16x8;
typedef __attribute__((ext_vector_type(4))) float f32x4;

__device__ __forceinline__ unsigned short f2bf(float f) {
    unsigned u = __float_as_uint(f);
    u = (u + 0x7FFFu + ((u >> 16) & 1u)) >> 16;
    return (unsigned short)u;
}
__device__ __forceinline__ float bf2f(unsigned short h) {
    return __uint_as_float(((unsigned)h) << 16);
}

// ---------------------------------------------------------------------------
// Kernel 1: conv1x1 q/k/v -> Ybf bf16 [b][o][n]. 16 outputs per block.
// grid (8, 20, 16), block 256.
__global__ __launch_bounds__(256) void conv_kernel(
    const float* __restrict__ x,
    const float* __restrict__ qw, const float* __restrict__ qb,
    const float* __restrict__ kw, const float* __restrict__ kb,
    const float* __restrict__ vw, const float* __restrict__ vb,
    unsigned short* __restrict__ Ybf)
{
    int n  = blockIdx.x * 256 + threadIdx.x;
    int o0 = blockIdx.y * 16;
    int b  = blockIdx.z;

    const float* wsrc; const float* bsrc; int oo;
    if (o0 < 32)      { wsrc = qw; bsrc = qb; oo = o0;      }
    else if (o0 < 64) { wsrc = kw; bsrc = kb; oo = o0 - 32; }
    else              { wsrc = vw; bsrc = vb; oo = o0 - 64; }
    const float* w0 = wsrc + (size_t)oo * CH;

    const float* xb = x + (size_t)b * CH * NPT + n;
    float a[16];
#pragma unroll
    for (int j = 0; j < 16; ++j) a[j] = 0.f;

#pragma unroll 4
    for (int c = 0; c < CH; ++c) {
        float xv = xb[(size_t)c * NPT];
#pragma unroll
        for (int j = 0; j < 16; ++j)
            a[j] = fmaf(w0[j * CH + c], xv, a[j]);
    }
    unsigned short* yb = Ybf + ((size_t)b * OTOT + o0) * NPT + n;
#pragma unroll
    for (int j = 0; j < 16; ++j)
        yb[(size_t)j * NPT] = f2bf(a[j] + bsrc[oo + j]);
}

// ---------------------------------------------------------------------------
// Kernel 2: BN stats over (B,N) from bf16 -> A[o], Cc[o].  grid 320, block 256.
__global__ __launch_bounds__(256) void stats_kernel(
    const unsigned short* __restrict__ Ybf,
    const float* __restrict__ qg, const float* __restrict__ qbe,
    const float* __restrict__ kg, const float* __restrict__ kbe,
    const float* __restrict__ vg, const float* __restrict__ vbe,
    float* __restrict__ A, float* __restrict__ Cc)
{
    int o = blockIdx.x;
    float s = 0.f, ss = 0.f;
    // BATCH*NPT/4 = 8192 ushort4 slots
    for (int t = threadIdx.x; t < (BATCH * NPT) / 4; t += 256) {
        int b = t >> 9, n4 = (t & 511) * 4;
        const ushort4 v4 = *(const ushort4*)(Ybf + ((size_t)b * OTOT + o) * NPT + n4);
        float f0 = bf2f(v4.x), f1 = bf2f(v4.y), f2 = bf2f(v4.z), f3 = bf2f(v4.w);
        s  += f0 + f1 + f2 + f3;
        ss += f0*f0 + f1*f1 + f2*f2 + f3*f3;
    }
#pragma unroll
    for (int off = 32; off; off >>= 1) {
        s  += __shfl_down(s, off);
        ss += __shfl_down(ss, off);
    }
    __shared__ float ls[4], lss[4];
    int w = threadIdx.x >> 6, lane = threadIdx.x & 63;
    if (lane == 0) { ls[w] = s; lss[w] = ss; }
    __syncthreads();
    if (threadIdx.x == 0) {
        float S  = ls[0] + ls[1] + ls[2] + ls[3];
        float SS = lss[0] + lss[1] + lss[2] + lss[3];
        const float inv = 1.0f / (BATCH * NPT);
        float mean = S * inv;
        float var  = SS * inv - mean * mean;
        float g, be;
        if (o < 32)      { g = qg[o];      be = qbe[o];      }
        else if (o < 64) { g = kg[o - 32]; be = kbe[o - 32]; }
        else             { g = vg[o - 64]; be = vbe[o - 64]; }
        float a = g * rsqrtf(var + EPSB);
        A[o]  = a;
        Cc[o] = be - mean * a;
    }
}

// ---------------------------------------------------------------------------
// Kernel 3: v channels: affine + LeakyReLU -> Vbf [b][c][n] bf16.
// grid 8192, block 256, 4 elems/thread.
__global__ __launch_bounds__(256) void normv_kernel(
    const unsigned short* __restrict__ Ybf,
    const float* __restrict__ A, const float* __restrict__ Cc,
    unsigned short* __restrict__ Vbf)
{
    size_t e = ((size_t)blockIdx.x * 256 + threadIdx.x) * 4;
    int b = (int)(e >> 19);
    int r = (int)(e & ((1u << 19) - 1));
    int c = r >> 11, n = r & (NPT - 1);
    const ushort4 v4 = *(const ushort4*)(Ybf + ((size_t)b * OTOT + 64 + c) * NPT + n);
    float a = A[64 + c], cc = Cc[64 + c];
    float f[4] = { bf2f(v4.x), bf2f(v4.y), bf2f(v4.z), bf2f(v4.w) };
    ushort4 o4;
    unsigned short* po = (unsigned short*)&o4;
#pragma unroll
    for (int i = 0; i < 4; ++i) {
        float y = f[i] * a + cc;
        y = (y > 0.f) ? y : SLOPE * y;
        po[i] = f2bf(y);
    }
    *(ushort4*)(Vbf + ((size_t)b * CH + c) * NPT + n) = o4;
}

// ---------------------------------------------------------------------------
// Kernel 4: q/k channels: affine + transpose -> QKt [b][n][64] bf16
// (cols 0..31 = q(d), 32..63 = k(d)).  grid (32, 16), block 256.
__global__ __launch_bounds__(256) void transpose_qk_kernel(
    const unsigned short* __restrict__ Ybf,
    const float* __restrict__ A, const float* __restrict__ Cc,
    unsigned short* __restrict__ QKt)
{
    __shared__ unsigned short T[64][72];
    int b = blockIdx.y, n0 = blockIdx.x * 64;
    for (int e = threadIdx.x; e < 4096; e += 256) {
        int o = e >> 6, nn = e & 63;
        float y = bf2f(Ybf[((size_t)b * OTOT + o) * NPT + n0 + nn]);
        T[nn][o] = f2bf(y * A[o] + Cc[o]);
    }
    __syncthreads();
    for (int e = threadIdx.x; e < 4096; e += 256) {
        int nn = e >> 6, o = e & 63;
        QKt[((size_t)b * NPT + n0 + nn) * 64 + o] = T[nn][o];
    }
}

// ---------------------------------------------------------------------------
// Kernel 5: MFMA flash attention, max-free softmax, + residual.
// grid 1024 (XCD-swizzled b,z,n0 decode), block 256 (4 waves).
// Wave w: S for key-subtile w*16; PV for c-range z*128 + w*32.
__global__ __launch_bounds__(256, 4) void attn_kernel(
    const unsigned short* __restrict__ QKt,
    const unsigned short* __restrict__ Vbf,
    const float* __restrict__ x,
    float* __restrict__ out)
{
    // decode so the 32 blocks sharing (b,z) land on one XCD (round-robin %8)
    int L = blockIdx.x;
    int xcd = L & 7, k = L >> 3;
    int gi = k >> 5, n0i = k & 31;
    int grp = xcd * 4 + gi;           // 0..31
    int b = grp >> 1, z = grp & 1;
    int n0 = n0i * 64;

    int tid = threadIdx.x;
    int w = tid >> 6, lane = tid & 63;
    int quad = lane >> 4, l16 = lane & 15;

    const unsigned short* QK = QKt + (size_t)b * NPT * 64;
    const unsigned short* V  = Vbf + ((size_t)b * CH + z * 128) * NPT;

    __shared__ unsigned short Pbf[64][72];
    __shared__ float rsw[4][64];
    __shared__ float rtot[64];

    // Q A-fragments (resident): row n = n0 + nt*16 + l16, k = d = quad*8..+7
    bf16x8 qa[4];
#pragma unroll
    for (int nt = 0; nt < 4; ++nt)
        qa[nt] = *(const bf16x8*)(QK + ((size_t)(n0 + nt * 16 + l16)) * 64 + quad * 8);

    f32x4 acc[4][2];
#pragma unroll
    for (int nt = 0; nt < 4; ++nt)
#pragma unroll
        for (int ct = 0; ct < 2; ++ct)
            acc[nt][ct] = (f32x4){0.f, 0.f, 0.f, 0.f};

    float rsum[4][4];
#pragma unroll
    for (int nt = 0; nt < 4; ++nt)
#pragma unroll
        for (int r = 0; r < 4; ++r) rsum[nt][r] = 0.f;

    const f32x4 zero4 = (f32x4){0.f, 0.f, 0.f, 0.f};

    for (int mt = 0; mt < NPT / 64; ++mt) {
        // K B-fragment: key m = mt*64 + w*16 + l16, d = quad*8..+7 (cols 32..63)
        bf16x8 kb = *(const bf16x8*)(QK + ((size_t)(mt * 64 + w * 16 + l16)) * 64 + 32 + quad * 8);

        __syncthreads();   // prev-iter PV reads of Pbf complete

        // S + exp + write P (C layout: row = quad*4+r, col = l16)
#pragma unroll
        for (int nt = 0; nt < 4; ++nt) {
            f32x4 s = __builtin_amdgcn_mfma_f32_16x16x32_bf16(qa[nt], kb, zero4, 0, 0, 0);
#pragma unroll
            for (int r = 0; r < 4; ++r) {
                float p = __expf(s[r]);         // max-free: |s| << 88
                rsum[nt][r] += p;
                Pbf[nt * 16 + quad * 4 + r][w * 16 + l16] = f2bf(p);
            }
        }
        __syncthreads();   // P visible

        // PV: O^T[n][c] += P[n][m] V^T[m][c]
#pragma unroll
        for (int ks = 0; ks < 2; ++ks) {
            bf16x8 pa[4];
#pragma unroll
            for (int nt = 0; nt < 4; ++nt)
                pa[nt] = *(const bf16x8*)&Pbf[nt * 16 + l16][ks * 32 + quad * 8];
#pragma unroll
            for (int ct = 0; ct < 2; ++ct) {
                const unsigned short* vp =
                    V + ((size_t)(w * 32 + ct * 16 + l16)) * NPT + mt * 64 + ks * 32 + quad * 8;
                bf16x8 vb = *(const bf16x8*)vp;
#pragma unroll
                for (int nt = 0; nt < 4; ++nt)
                    acc[nt][ct] = __builtin_amdgcn_mfma_f32_16x16x32_bf16(pa[nt], vb, acc[nt][ct], 0, 0, 0);
            }
        }
    }

    // row-sum reduction: 16 col-lanes (xor within quad group) then cross-wave
#pragma unroll
    for (int nt = 0; nt < 4; ++nt)
#pragma unroll
        for (int r = 0; r < 4; ++r) {
            float v = rsum[nt][r];
            v += __shfl_xor(v, 1);
            v += __shfl_xor(v, 2);
            v += __shfl_xor(v, 4);
            v += __shfl_xor(v, 8);
            if (l16 == 0) rsw[w][nt * 16 + quad * 4 + r] = v;
        }
    __syncthreads();
    if (tid < 64)
        rtot[tid] = 1.0f / (rsw[0][tid] + rsw[1][tid] + rsw[2][tid] + rsw[3][tid]);
    __syncthreads();

    // epilogue: O * (1/rowsum) + x, float4 stores (regs r are consecutive n)
    float rin[4][4];
#pragma unroll
    for (int nt = 0; nt < 4; ++nt)
#pragma unroll
        for (int r = 0; r < 4; ++r) rin[nt][r] = rtot[nt * 16 + quad * 4 + r];

#pragma unroll
    for (int nt = 0; nt < 4; ++nt)
#pragma unroll
        for (int ct = 0; ct < 2; ++ct) {
            int c = z * 128 + w * 32 + ct * 16 + l16;
            int n = n0 + nt * 16 + quad * 4;
            size_t gi4 = ((size_t)b * CH + c) * NPT + n;
            float4 xv = *(const float4*)(x + gi4);
            float4 o;
            o.x = acc[nt][ct][0] * rin[nt][0] + xv.x;
            o.y = acc[nt][ct][1] * rin[nt][1] + xv.y;
            o.z = acc[nt][ct][2] * rin[nt][2] + xv.z;
            o.w = acc[nt][ct][3] * rin[nt][3] + xv.w;
            *(float4*)(out + gi4) = o;
        }
}

// ---------------------------------------------------------------------------
extern "C" void kernel_launch(void* const* d_in, const int* in_sizes, int n_in,
                              void* d_out, int out_size, void* d_ws, size_t ws_size,
                              hipStream_t stream)
{
    const float* x   = (const float*)d_in[0];
    const float* qw  = (const float*)d_in[1];
    const float* qb  = (const float*)d_in[2];
    const float* qg  = (const float*)d_in[3];
    const float* qbe = (const float*)d_in[4];
    const float* kw  = (const float*)d_in[5];
    const float* kb  = (const float*)d_in[6];
    const float* kg  = (const float*)d_in[7];
    const float* kbe = (const float*)d_in[8];
    const float* vw  = (const float*)d_in[9];
    const float* vb  = (const float*)d_in[10];
    const float* vg  = (const float*)d_in[11];
    const float* vbe = (const float*)d_in[12];
    float* out = (float*)d_out;

    // ws: Ybf bf16 [16][320][2048] (20.97MB) | QKt bf16 (4.19MB) | Vbf bf16 (16.78MB) | A,Cc
    unsigned short* Ybf = (unsigned short*)d_ws;
    unsigned short* QKt = Ybf + (size_t)BATCH * OTOT * NPT;          // 10485760 elems
    unsigned short* Vbf = QKt + (size_t)BATCH * NPT * 64;            // +2097152
    float* A  = (float*)(Vbf + (size_t)BATCH * CH * NPT);            // +8388608
    float* Cc = A + OTOT;

    conv_kernel <<<dim3(NPT / 256, OTOT / 16, BATCH), 256, 0, stream>>>(x, qw, qb, kw, kb, vw, vb, Ybf);
    stats_kernel<<<OTOT, 256, 0, stream>>>(Ybf, qg, qbe, kg, kbe, vg, vbe, A, Cc);
    normv_kernel<<<(BATCH * CH * NPT) / 1024, 256, 0, stream>>>(Ybf, A, Cc, Vbf);
    transpose_qk_kernel<<<dim3(NPT / 64, BATCH), 256, 0, stream>>>(Ybf, A, Cc, QKt);
    attn_kernel <<<1024, 256, 0, stream>>>(QKt, Vbf, x, out);
}